// Round 4
// baseline (1456.315 us; speedup 1.0000x reference)
//
#include <hip/hip_runtime.h>
#include <cstdint>

// ODE Euler scan: B=1024, T=4096, S=8, E=8, H=32.
// One wave per batch element; 1024 blocks x 64 threads = 1 wave/SIMD.
// Lane l owns hidden units a=g, b=g+16 (g=l&15); full y replicated per lane;
// 16-lane all-lanes DPP butterfly for the H-reduction (no DS on the chain).
// Round 4: round-3 structure (scalar FMAs, 2-step-ahead LDS prefetch, lean
// y-record) with the PROVEN exp2-based tanh (Pade(5,4) failed absmax 1.078).

#if __has_builtin(__builtin_amdgcn_exp2f)
#define EXP2F(v) __builtin_amdgcn_exp2f(v)
#else
#define EXP2F(v) __exp2f(v)
#endif
#if __has_builtin(__builtin_amdgcn_rcpf)
#define RCPF(v) __builtin_amdgcn_rcpf(v)
#else
#define RCPF(v) (1.0f / (v))
#endif

template <int CTRL>
__device__ __forceinline__ float dpp_add(float x) {
  int sh = __builtin_amdgcn_update_dpp(0, __float_as_int(x), CTRL, 0xF, 0xF, true);
  return x + __int_as_float(sh);
}

// Sum over each 16-lane group; result valid in ALL lanes of the group.
__device__ __forceinline__ float reduce16_all(float x) {
  x = dpp_add<0xB1>(x);   // quad_perm [1,0,3,2] : lane ^ 1
  x = dpp_add<0x4E>(x);   // quad_perm [2,3,0,1] : lane ^ 2
  x = dpp_add<0x141>(x);  // row_half_mirror     : lane ^ 4
  x = dpp_add<0x140>(x);  // row_mirror          : lane ^ 8
  return x;
}

// tanh(v) = 1 - 2/(exp2(2v*log2e)+1)  — proven absmax 0.25 in rounds 1-2.
__device__ __forceinline__ float tanh_exp(float z) {
  float u = EXP2F(z * 2.885390081777927f);
  return fmaf(-2.0f, RCPF(u + 1.0f), 1.0f);
}

__global__ __launch_bounds__(64, 1) void ode_scan_kernel(
    const float* __restrict__ x, const float* __restrict__ t,
    const float* __restrict__ y0, const float* __restrict__ Wr1,
    const float* __restrict__ br1, const float* __restrict__ Wr2,
    const float* __restrict__ br2, const float* __restrict__ W1,
    const float* __restrict__ b1, const float* __restrict__ W2,
    const float* __restrict__ b2, float* __restrict__ out) {
  constexpr int T = 4096;

  __shared__ __align__(16) float t_lds[4096];      // t, then dt in-place
  __shared__ __align__(16) float xbuf[2 * 64 * 8]; // double-buffered x chunks
  __shared__ __align__(16) float ybuf[64 * 12];    // 64 y-slots, stride 12
  __shared__ float hw[112];                        // W1(80) b1(10) W2(20) b2(2)

  const int l = threadIdx.x;
  const int b = blockIdx.x;
  const int g = l & 15;
  const int ua = g;        // first owned hidden unit
  const int ub = g + 16;   // second owned hidden unit

  // ---- stage t into LDS ----
  const float4* t4 = (const float4*)t;
  #pragma unroll
  for (int it = 0; it < 16; ++it) {
    float4 v = t4[it * 64 + l];
    *(float4*)&t_lds[(it * 64 + l) * 4] = v;
  }
  // dt in place (single wave => DS ops in program order)
  for (int it = 0; it < 64; ++it) {
    int i = it * 64 + l;
    float aa = t_lds[i];
    float cc = (i < T - 1) ? t_lds[i + 1] : 0.0f;
    t_lds[i] = cc - aa;  // slot 4095 garbage; never consumed
  }

  // ---- head weights into LDS ----
  for (int v = l; v < 112; v += 64) {
    float w;
    if (v < 80) w = W1[v];
    else if (v < 90) w = b1[v - 80];
    else if (v < 110) w = W2[v - 90];
    else w = b2[v - 110];
    hw[v] = w;
  }

  // ---- per-lane recurrence weights (scalar, units a and b) ----
  float wya[8], wyb[8], wea[8], web[8], w2a[8], w2b[8], br2s[8];
  #pragma unroll
  for (int s = 0; s < 8; ++s) {
    wya[s] = Wr1[s * 32 + ua];
    wyb[s] = Wr1[s * 32 + ub];
    wea[s] = Wr1[(8 + s) * 32 + ua];
    web[s] = Wr1[(8 + s) * 32 + ub];
    w2a[s] = Wr2[ua * 8 + s];
    w2b[s] = Wr2[ub * 8 + s];
    br2s[s] = (g == 0) ? br2[s] : 0.0f;  // one lane per 16-group carries br2
  }
  const float br1a = br1[ua];
  const float br1b = br1[ub];

  // ---- full y state per lane ----
  float y[8];
  #pragma unroll
  for (int s = 0; s < 8; ++s) y[s] = y0[b * 8 + s];

  // ---- stage x chunk 0 ----
  const float* xbase = x + (size_t)b * (T * 8);
  {
    float4 a0 = *(const float4*)&xbase[l * 8 + 0];
    float4 a1 = *(const float4*)&xbase[l * 8 + 4];
    *(float4*)&xbuf[l * 8 + 0] = a0;
    *(float4*)&xbuf[l * 8 + 4] = a1;
  }

  // record y0 into slot 0
  if (l == 0) {
    #pragma unroll
    for (int s = 0; s < 8; ++s) ybuf[s] = y[s];
  }

  float2* out2 = (float2*)out + (size_t)b * T;

  // 2-deep prefetch: ec = e_0 (consumed at step 1), en = e_1.
  float4 ec0 = *(float4*)&xbuf[0];
  float4 ec1 = *(float4*)&xbuf[4];
  float dtc = t_lds[0];
  float4 en0 = *(float4*)&xbuf[8];
  float4 en1 = *(float4*)&xbuf[12];
  float dtn = t_lds[1];

  #pragma unroll 1
  for (int c = 0; c < 64; ++c) {
    float4 g0 = make_float4(0.f, 0.f, 0.f, 0.f), g1 = g0;
    if (c < 63) {
      g0 = *(const float4*)&xbase[(c + 1) * 512 + l * 8 + 0];
      g1 = *(const float4*)&xbase[(c + 1) * 512 + l * 8 + 4];
    }

    auto step = [&](int k) {
      const int inext = c * 64 + k;  // computing y_{inext} from y_{inext-1}
      // issue loads for e_{inext+1} / dt_{inext+1} (consumed 2 steps later)
      float4 f0 = *(float4*)&xbuf[((inext + 1) & 127) * 8 + 0];
      float4 f1 = *(float4*)&xbuf[((inext + 1) & 127) * 8 + 4];
      float fdt = t_lds[(inext + 1) & 4095];

      // e-dot (off chain): br1 + e . We, two 4-chains per unit
      float ea1 = fmaf(ec0.x, wea[0], br1a);
      ea1 = fmaf(ec0.y, wea[1], ea1);
      ea1 = fmaf(ec0.z, wea[2], ea1);
      ea1 = fmaf(ec0.w, wea[3], ea1);
      float ea2 = ec1.x * wea[4];
      ea2 = fmaf(ec1.y, wea[5], ea2);
      ea2 = fmaf(ec1.z, wea[6], ea2);
      ea2 = fmaf(ec1.w, wea[7], ea2);
      float eb1 = fmaf(ec0.x, web[0], br1b);
      eb1 = fmaf(ec0.y, web[1], eb1);
      eb1 = fmaf(ec0.z, web[2], eb1);
      eb1 = fmaf(ec0.w, web[3], eb1);
      float eb2 = ec1.x * web[4];
      eb2 = fmaf(ec1.y, web[5], eb2);
      eb2 = fmaf(ec1.z, web[6], eb2);
      eb2 = fmaf(ec1.w, web[7], eb2);

      // y-dot (on chain): two 4-chains per unit
      float ya1 = y[0] * wya[0];
      ya1 = fmaf(y[1], wya[1], ya1);
      ya1 = fmaf(y[2], wya[2], ya1);
      ya1 = fmaf(y[3], wya[3], ya1);
      float ya2 = y[4] * wya[4];
      ya2 = fmaf(y[5], wya[5], ya2);
      ya2 = fmaf(y[6], wya[6], ya2);
      ya2 = fmaf(y[7], wya[7], ya2);
      float yb1 = y[0] * wyb[0];
      yb1 = fmaf(y[1], wyb[1], yb1);
      yb1 = fmaf(y[2], wyb[2], yb1);
      yb1 = fmaf(y[3], wyb[3], yb1);
      float yb2 = y[4] * wyb[4];
      yb2 = fmaf(y[5], wyb[5], yb2);
      yb2 = fmaf(y[6], wyb[6], yb2);
      yb2 = fmaf(y[7], wyb[7], yb2);

      float za = (ea1 + ea2) + (ya1 + ya2);
      float zb = (eb1 + eb2) + (yb1 + yb2);

      float ha = tanh_exp(za);
      float hb = tanh_exp(zb);

      // partials + 16-lane butterfly => full 32-unit sums in every lane
      float p[8];
      #pragma unroll
      for (int s = 0; s < 8; ++s)
        p[s] = fmaf(ha, w2a[s], fmaf(hb, w2b[s], br2s[s]));
      #pragma unroll
      for (int s = 0; s < 8; ++s) p[s] = reduce16_all(p[s]);

      // Euler update (all lanes hold full y)
      #pragma unroll
      for (int s = 0; s < 8; ++s) y[s] = fmaf(dtc, p[s], y[s]);

      // record y_{inext} into slot k (lane 0; scalar stores -> ds_write2 pairs)
      if (l == 0) {
        #pragma unroll
        for (int s = 0; s < 8; ++s) ybuf[k * 12 + s] = y[s];
      }

      // rotate prefetch pipeline
      ec0 = en0; ec1 = en1; dtc = dtn;
      en0 = f0;  en1 = f1;  dtn = fdt;
    };

    #pragma unroll 2
    for (int k = (c ? 0 : 1); k < 8; ++k) step(k);

    if (c < 63) {
      *(float4*)&xbuf[((c + 1) & 1) * 512 + l * 8 + 0] = g0;
      *(float4*)&xbuf[((c + 1) & 1) * 512 + l * 8 + 4] = g1;
    }

    #pragma unroll 2
    for (int k = 8; k < 64; ++k) step(k);

    // ---- head burst: lane l handles tau = c*64 + l ----
    {
      float4 ya = *(float4*)&ybuf[l * 12 + 0];
      float4 yb = *(float4*)&ybuf[l * 12 + 4];
      float ys[8] = {ya.x, ya.y, ya.z, ya.w, yb.x, yb.y, yb.z, yb.w};
      float o0 = hw[110], o1 = hw[111];
      #pragma unroll
      for (int m = 0; m < 10; ++m) {
        float hh = hw[80 + m];
        #pragma unroll
        for (int s = 0; s < 8; ++s) hh = fmaf(ys[s], hw[s * 10 + m], hh);
        hh = fmaxf(hh, 0.0f);
        o0 = fmaf(hh, hw[90 + m * 2 + 0], o0);
        o1 = fmaf(hh, hw[90 + m * 2 + 1], o1);
      }
      out2[c * 64 + l] = make_float2(o0, o1);
    }
  }
}

extern "C" void kernel_launch(void* const* d_in, const int* in_sizes, int n_in,
                              void* d_out, int out_size, void* d_ws, size_t ws_size,
                              hipStream_t stream) {
  const float* x   = (const float*)d_in[0];
  const float* t   = (const float*)d_in[1];
  const float* y0  = (const float*)d_in[2];
  const float* Wr1 = (const float*)d_in[3];
  const float* br1 = (const float*)d_in[4];
  const float* Wr2 = (const float*)d_in[5];
  const float* br2 = (const float*)d_in[6];
  const float* W1  = (const float*)d_in[7];
  const float* b1  = (const float*)d_in[8];
  const float* W2  = (const float*)d_in[9];
  const float* b2  = (const float*)d_in[10];
  (void)in_sizes; (void)n_in; (void)out_size; (void)d_ws; (void)ws_size;

  ode_scan_kernel<<<dim3(1024), dim3(64), 0, stream>>>(x, t, y0, Wr1, br1, Wr2,
                                                       br2, W1, b1, W2, b2,
                                                       (float*)d_out);
}

// Round 5
// 1201.830 us; speedup vs baseline: 1.2117x; 1.2117x over previous
//
#include <hip/hip_runtime.h>
#include <cstdint>

// ODE Euler scan: B=1024, T=4096, S=8, E=8, H=32.
// One wave per batch element; 1024 blocks x 64 threads = 1 wave/SIMD.
// Round 5: R1's minimal-issue layout (lane owns unit j=l&31; halves own
// s-quads for the Wr2 partials; 20-DPP reduce32) with the ds_bpermute
// broadcast replaced by 8 v_readlane -> SGPR sums; every lane keeps a full
// private y[8] updated by v_add(v,s,v). dt folded into h/br2 pre-reduction.
// 1-deep LDS prefetch + unroll-2 register renaming (no rotate movs).

#if __has_builtin(__builtin_amdgcn_exp2f)
#define EXP2F(v) __builtin_amdgcn_exp2f(v)
#else
#define EXP2F(v) __exp2f(v)
#endif
#if __has_builtin(__builtin_amdgcn_rcpf)
#define RCPF(v) __builtin_amdgcn_rcpf(v)
#else
#define RCPF(v) (1.0f / (v))
#endif

template <int CTRL, int RM>
__device__ __forceinline__ float dpp_add(float x) {
  // old=0 so disabled rows / out-of-range sources contribute 0 either way.
  int sh = __builtin_amdgcn_update_dpp(0, __float_as_int(x), CTRL, RM, 0xF, true);
  return x + __int_as_float(sh);
}

// Sum over each 32-lane half; result valid in lane 31 (half 0) / lane 63 (half 1).
// Exact structure proven correct in round 1 (absmax 0.25).
__device__ __forceinline__ float reduce32(float x) {
  x = dpp_add<0x111, 0xF>(x);  // row_shr:1
  x = dpp_add<0x112, 0xF>(x);  // row_shr:2
  x = dpp_add<0x114, 0xF>(x);  // row_shr:4
  x = dpp_add<0x118, 0xF>(x);  // row_shr:8  -> lanes 15/31/47/63 hold row sums
  x = dpp_add<0x142, 0xA>(x);  // row_bcast15 into rows 1,3 -> lanes 31/63
  return x;
}

__device__ __forceinline__ float rdlane(float v, int lane) {
  return __int_as_float(__builtin_amdgcn_readlane(__float_as_int(v), lane));
}

// tanh(v) = 1 - 2/(exp2(2v*log2e)+1)  — proven absmax 0.25.
__device__ __forceinline__ float tanh_exp(float z) {
  float u = EXP2F(z * 2.885390081777927f);
  return fmaf(-2.0f, RCPF(u + 1.0f), 1.0f);
}

__global__ __launch_bounds__(64, 1) void ode_scan_kernel(
    const float* __restrict__ x, const float* __restrict__ t,
    const float* __restrict__ y0, const float* __restrict__ Wr1,
    const float* __restrict__ br1, const float* __restrict__ Wr2,
    const float* __restrict__ br2, const float* __restrict__ W1,
    const float* __restrict__ b1, const float* __restrict__ W2,
    const float* __restrict__ b2, float* __restrict__ out) {
  constexpr int T = 4096;

  __shared__ __align__(16) float t_lds[4096];      // t, then dt in-place
  __shared__ __align__(16) float xbuf[2 * 64 * 8]; // double-buffered x chunks
  __shared__ __align__(16) float ybuf[64 * 12];    // 64 y-slots, stride 12
  __shared__ float hw[112];                        // W1(80) b1(10) W2(20) b2(2)

  const int l = threadIdx.x;
  const int b = blockIdx.x;
  const int j = l & 31;     // owned hidden unit
  const int half = l >> 5;
  const int sq = half * 4;  // owned s-quad for partials (half0: s0-3, half1: s4-7)

  // ---- stage t into LDS ----
  const float4* t4 = (const float4*)t;
  #pragma unroll
  for (int it = 0; it < 16; ++it) {
    float4 v = t4[it * 64 + l];
    *(float4*)&t_lds[(it * 64 + l) * 4] = v;
  }
  // dt in place (single wave => DS ops in program order)
  for (int it = 0; it < 64; ++it) {
    int i = it * 64 + l;
    float aa = t_lds[i];
    float cc = (i < T - 1) ? t_lds[i + 1] : 0.0f;
    t_lds[i] = cc - aa;  // slot 4095 garbage; never consumed
  }

  // ---- head weights into LDS ----
  for (int v = l; v < 112; v += 64) {
    float w;
    if (v < 80) w = W1[v];
    else if (v < 90) w = b1[v - 80];
    else if (v < 110) w = W2[v - 90];
    else w = b2[v - 110];
    hw[v] = w;
  }

  // ---- per-lane recurrence weights ----
  float wy[8], we[8], w2q[4], br2q[4];
  #pragma unroll
  for (int s = 0; s < 8; ++s) {
    wy[s] = Wr1[s * 32 + j];
    we[s] = Wr1[(8 + s) * 32 + j];
  }
  #pragma unroll
  for (int q = 0; q < 4; ++q) {
    w2q[q] = Wr2[j * 8 + sq + q];
    br2q[q] = (j == 0) ? br2[sq + q] : 0.0f;  // lane j==0 of each half carries br2
  }
  const float br1j = br1[j];

  // ---- full y state per lane (identical in all lanes) ----
  float y[8];
  #pragma unroll
  for (int s = 0; s < 8; ++s) y[s] = y0[b * 8 + s];

  // ---- stage x chunk 0 ----
  const float* xbase = x + (size_t)b * (T * 8);
  {
    float4 a0 = *(const float4*)&xbase[l * 8 + 0];
    float4 a1 = *(const float4*)&xbase[l * 8 + 4];
    *(float4*)&xbuf[l * 8 + 0] = a0;
    *(float4*)&xbuf[l * 8 + 4] = a1;
  }

  // record y0 into slot 0
  if (l == 0) {
    #pragma unroll
    for (int s = 0; s < 8; ++s) ybuf[s] = y[s];
  }

  float2* out2 = (float2*)out + (size_t)b * T;

  // 1-deep prefetch: ec/dtc are for the upcoming step (e_{i-1}, dt_{i-1} of y_i).
  float4 ec0 = *(float4*)&xbuf[0];
  float4 ec1 = *(float4*)&xbuf[4];
  float dtc = t_lds[0];

  #pragma unroll 1
  for (int c = 0; c < 64; ++c) {
    float4 g0 = make_float4(0.f, 0.f, 0.f, 0.f), g1 = g0;
    if (c < 63) {
      g0 = *(const float4*)&xbase[(c + 1) * 512 + l * 8 + 0];
      g1 = *(const float4*)&xbase[(c + 1) * 512 + l * 8 + 4];
    }

    auto step = [&](int k) {
      const int inext = c * 64 + k;  // computing y_{inext} from y_{inext-1}
      // prefetch e_{inext}/dt_{inext} for the next step (1-deep, renamed by unroll 2)
      float4 ne0 = *(float4*)&xbuf[(inext & 127) * 8 + 0];
      float4 ne1 = *(float4*)&xbuf[(inext & 127) * 8 + 4];
      float ndt = t_lds[inext];

      // e-dot (off chain): br1 + e . we, two 4-chains
      float ed = fmaf(ec0.x, we[0], br1j);
      ed = fmaf(ec0.y, we[1], ed);
      ed = fmaf(ec0.z, we[2], ed);
      ed = fmaf(ec0.w, we[3], ed);
      float ed2 = ec1.x * we[4];
      ed2 = fmaf(ec1.y, we[5], ed2);
      ed2 = fmaf(ec1.z, we[6], ed2);
      ed2 = fmaf(ec1.w, we[7], ed2);

      // y-dot (on chain): two 4-chains
      float yd = y[0] * wy[0];
      yd = fmaf(y[1], wy[1], yd);
      yd = fmaf(y[2], wy[2], yd);
      yd = fmaf(y[3], wy[3], yd);
      float yd2 = y[4] * wy[4];
      yd2 = fmaf(y[5], wy[5], yd2);
      yd2 = fmaf(y[6], wy[6], yd2);
      yd2 = fmaf(y[7], wy[7], yd2);

      float acc = (ed + ed2) + (yd + yd2);
      float h = tanh_exp(acc);

      // fold dt before the reduction: hp = h*dt, br2 term pre-scaled
      float hp = h * dtc;
      float r0 = reduce32(fmaf(hp, w2q[0], dtc * br2q[0]));
      float r1 = reduce32(fmaf(hp, w2q[1], dtc * br2q[1]));
      float r2 = reduce32(fmaf(hp, w2q[2], dtc * br2q[2]));
      float r3 = reduce32(fmaf(hp, w2q[3], dtc * br2q[3]));

      // 8 wave-uniform sums via readlane (no DS round-trip); Euler = v_add(v,s,v)
      y[0] += rdlane(r0, 31);
      y[1] += rdlane(r1, 31);
      y[2] += rdlane(r2, 31);
      y[3] += rdlane(r3, 31);
      y[4] += rdlane(r0, 63);
      y[5] += rdlane(r1, 63);
      y[6] += rdlane(r2, 63);
      y[7] += rdlane(r3, 63);

      // record y_{inext} into slot k (after the prefetch reads; off-chain)
      if (l == 0) {
        #pragma unroll
        for (int s = 0; s < 8; ++s) ybuf[k * 12 + s] = y[s];
      }

      ec0 = ne0; ec1 = ne1; dtc = ndt;  // renamed away by unroll 2
    };

    #pragma unroll 2
    for (int k = (c ? 0 : 1); k < 8; ++k) step(k);

    if (c < 63) {
      *(float4*)&xbuf[((c + 1) & 1) * 512 + l * 8 + 0] = g0;
      *(float4*)&xbuf[((c + 1) & 1) * 512 + l * 8 + 4] = g1;
    }

    #pragma unroll 2
    for (int k = 8; k < 64; ++k) step(k);

    // ---- head burst: lane l handles tau = c*64 + l ----
    {
      float4 ya = *(float4*)&ybuf[l * 12 + 0];
      float4 yb = *(float4*)&ybuf[l * 12 + 4];
      float ys[8] = {ya.x, ya.y, ya.z, ya.w, yb.x, yb.y, yb.z, yb.w};
      float o0 = hw[110], o1 = hw[111];
      #pragma unroll
      for (int m = 0; m < 10; ++m) {
        float hh = hw[80 + m];
        #pragma unroll
        for (int s = 0; s < 8; ++s) hh = fmaf(ys[s], hw[s * 10 + m], hh);
        hh = fmaxf(hh, 0.0f);
        o0 = fmaf(hh, hw[90 + m * 2 + 0], o0);
        o1 = fmaf(hh, hw[90 + m * 2 + 1], o1);
      }
      out2[c * 64 + l] = make_float2(o0, o1);
    }
  }
}

extern "C" void kernel_launch(void* const* d_in, const int* in_sizes, int n_in,
                              void* d_out, int out_size, void* d_ws, size_t ws_size,
                              hipStream_t stream) {
  const float* x   = (const float*)d_in[0];
  const float* t   = (const float*)d_in[1];
  const float* y0  = (const float*)d_in[2];
  const float* Wr1 = (const float*)d_in[3];
  const float* br1 = (const float*)d_in[4];
  const float* Wr2 = (const float*)d_in[5];
  const float* br2 = (const float*)d_in[6];
  const float* W1  = (const float*)d_in[7];
  const float* b1  = (const float*)d_in[8];
  const float* W2  = (const float*)d_in[9];
  const float* b2  = (const float*)d_in[10];
  (void)in_sizes; (void)n_in; (void)out_size; (void)d_ws; (void)ws_size;

  ode_scan_kernel<<<dim3(1024), dim3(64), 0, stream>>>(x, t, y0, Wr1, br1, Wr2,
                                                       br2, W1, b1, W2, b2,
                                                       (float*)d_out);
}

// Round 6
// 852.141 us; speedup vs baseline: 1.7090x; 1.4104x over previous
//
#include <hip/hip_runtime.h>
#include <cstdint>

// ODE Euler scan: B=1024, T=4096, S=8, E=8, H=32.
// One wave per batch element; 1024 blocks x 64 threads = 1 wave/SIMD.
// Model (R1-R5 evidence): solo wave issues 1 inst / 4 cyc -> duration ~=
// 4 * total insts. R6 minimizes instruction count: pk_fma pairs for the
// dots, register ysave latch (no LDS record), dt post-folded, A/B e-buffer
// (no rotate movs), small non-unrolled pair loop.

typedef float v2f __attribute__((ext_vector_type(2)));

#define EXP2F(v) __builtin_amdgcn_exp2f(v)
#define RCPF(v) __builtin_amdgcn_rcpf(v)

__device__ __forceinline__ v2f fma2(v2f a, v2f b, v2f c) {
  return __builtin_elementwise_fma(a, b, c);
}

template <int CTRL, int RM>
__device__ __forceinline__ float dpp_add(float x) {
  int sh = __builtin_amdgcn_update_dpp(0, __float_as_int(x), CTRL, RM, 0xF, true);
  return x + __int_as_float(sh);
}

// Sum over each 32-lane half; valid in lane 31 (half 0) / 63 (half 1). Proven R1/R5.
__device__ __forceinline__ float reduce32(float x) {
  x = dpp_add<0x111, 0xF>(x);  // row_shr:1
  x = dpp_add<0x112, 0xF>(x);  // row_shr:2
  x = dpp_add<0x114, 0xF>(x);  // row_shr:4
  x = dpp_add<0x118, 0xF>(x);  // row_shr:8
  x = dpp_add<0x142, 0xA>(x);  // row_bcast15 -> lanes 31/63
  return x;
}

__device__ __forceinline__ float rdlane(float v, int lane) {
  return __int_as_float(__builtin_amdgcn_readlane(__float_as_int(v), lane));
}

// tanh(v) = 1 - 2/(exp2(2v*log2e)+1) — proven absmax 0.25.
__device__ __forceinline__ float tanh_exp(float z) {
  float u = EXP2F(z * 2.885390081777927f);
  return fmaf(-2.0f, RCPF(u + 1.0f), 1.0f);
}

__global__ __launch_bounds__(64, 1) void ode_scan_kernel(
    const float* __restrict__ x, const float* __restrict__ t,
    const float* __restrict__ y0, const float* __restrict__ Wr1,
    const float* __restrict__ br1, const float* __restrict__ Wr2,
    const float* __restrict__ br2, const float* __restrict__ W1,
    const float* __restrict__ b1, const float* __restrict__ W2,
    const float* __restrict__ b2, float* __restrict__ out) {
  constexpr int T = 4096;

  __shared__ __align__(16) float t_lds[4096];      // t, then dt in-place
  __shared__ __align__(16) float xbuf[2 * 64 * 8]; // double-buffered x chunks
  __shared__ float hw[112];                        // W1(80) b1(10) W2(20) b2(2)

  const int l = threadIdx.x;
  const int b = blockIdx.x;
  const int j = l & 31;     // owned hidden unit
  const int half = l >> 5;
  const int sq = half * 4;  // owned s-quad (half0: s0-3, half1: s4-7)

  // ---- stage t into LDS; dt in place (proven R5; single-wave DS in-order) ----
  const float4* t4 = (const float4*)t;
  #pragma unroll
  for (int it = 0; it < 16; ++it) {
    float4 v = t4[it * 64 + l];
    *(float4*)&t_lds[(it * 64 + l) * 4] = v;
  }
  for (int it = 0; it < 64; ++it) {
    int i = it * 64 + l;
    float aa = t_lds[i];
    float cc = (i < T - 1) ? t_lds[i + 1] : 0.0f;
    t_lds[i] = cc - aa;  // slot 4095 garbage; never consumed
  }

  // ---- head weights into LDS ----
  for (int v = l; v < 112; v += 64) {
    float w;
    if (v < 80) w = W1[v];
    else if (v < 90) w = b1[v - 80];
    else if (v < 110) w = W2[v - 90];
    else w = b2[v - 110];
    hw[v] = w;
  }

  // ---- per-lane weights: pk pairs over the summation index ----
  v2f wy2[4], we2[4];
  #pragma unroll
  for (int q = 0; q < 4; ++q) {
    wy2[q].x = Wr1[(2 * q) * 32 + j];
    wy2[q].y = Wr1[(2 * q + 1) * 32 + j];
    we2[q].x = Wr1[(8 + 2 * q) * 32 + j];
    we2[q].y = Wr1[(8 + 2 * q + 1) * 32 + j];
  }
  float w2q[4], br2q[4];
  #pragma unroll
  for (int q = 0; q < 4; ++q) {
    w2q[q] = Wr2[j * 8 + sq + q];
    br2q[q] = (j == 0) ? br2[sq + q] : 0.0f;  // lane j==0 per half carries br2
  }
  v2f br1h; br1h.x = br1[j]; br1h.y = 0.0f;

  // ---- y state as 4 pairs, replicated in all lanes; ysave latch in regs ----
  v2f y2[4], ysv[4];
  #pragma unroll
  for (int q = 0; q < 4; ++q) {
    y2[q].x = y0[b * 8 + 2 * q];
    y2[q].y = y0[b * 8 + 2 * q + 1];
    ysv[q] = y2[q];  // lane 0's tau=0 prime (other lanes latched before use)
  }

  // ---- stage x chunk 0 ----
  const float* xbase = x + (size_t)b * (T * 8);
  {
    float4 a0 = *(const float4*)&xbase[l * 8 + 0];
    float4 a1 = *(const float4*)&xbase[l * 8 + 4];
    *(float4*)&xbuf[l * 8 + 0] = a0;
    *(float4*)&xbuf[l * 8 + 4] = a1;
  }

  float2* out2 = (float2*)out + (size_t)b * T;

  // e/dt buffers: A/B manual double-buffer (no rotate movs).
  struct EB { v2f e0, e1, e2, e3; float dt; };
  EB P, Q;
  {
    float4 a0 = *(float4*)&xbuf[0];
    float4 a1 = *(float4*)&xbuf[4];
    P.e0.x = a0.x; P.e0.y = a0.y; P.e1.x = a0.z; P.e1.y = a0.w;
    P.e2.x = a1.x; P.e2.y = a1.y; P.e3.x = a1.z; P.e3.y = a1.w;
    P.dt = t_lds[0];
  }

  #pragma unroll 1
  for (int c = 0; c < 64; ++c) {
    const bool more = (c < 63);
    float4 g0 = make_float4(0.f, 0.f, 0.f, 0.f), g1 = g0;
    if (more) {
      g0 = *(const float4*)&xbase[(c + 1) * 512 + l * 8 + 0];
      g1 = *(const float4*)&xbase[(c + 1) * 512 + l * 8 + 4];
    }

    // step: computes y_{c*64+k+1}, consuming e_i/dt_i (i=c*64+k) from `in`;
    // prefetches slot i+1 into `o`. Latches lane (k+1)&63's ysave.
    auto step = [&](int k, const EB& in, EB& o) {
      const int inx = c * 64 + k + 1;
      const int slot = inx & 127;
      float4 f0 = *(float4*)&xbuf[slot * 8 + 0];
      float4 f1 = *(float4*)&xbuf[slot * 8 + 4];
      float fdt = t_lds[inx & 4095];

      // z = br1 + e.We + y.Wy  (pk pairs over the summation index)
      v2f ze = fma2(in.e0, we2[0], br1h);
      ze = fma2(in.e1, we2[1], ze);
      ze = fma2(in.e2, we2[2], ze);
      ze = fma2(in.e3, we2[3], ze);
      v2f zy = y2[0] * wy2[0];
      zy = fma2(y2[1], wy2[1], zy);
      zy = fma2(y2[2], wy2[2], zy);
      zy = fma2(y2[3], wy2[3], zy);
      v2f z2 = ze + zy;
      float z = z2.x + z2.y;

      float h = tanh_exp(z);

      // partials (dt NOT folded; br2 rides on lane j==0) + 32-lane reduce
      float p0 = reduce32(fmaf(h, w2q[0], br2q[0]));
      float p1 = reduce32(fmaf(h, w2q[1], br2q[1]));
      float p2 = reduce32(fmaf(h, w2q[2], br2q[2]));
      float p3 = reduce32(fmaf(h, w2q[3], br2q[3]));

      // stash prefetch into o (regs; off-chain)
      o.e0.x = f0.x; o.e0.y = f0.y; o.e1.x = f0.z; o.e1.y = f0.w;
      o.e2.x = f1.x; o.e2.y = f1.y; o.e3.x = f1.z; o.e3.y = f1.w;
      o.dt = fdt;

      // y_s += dt * r_s   (r via readlane -> SGPR; v_fma v,s,v)
      float dtv = in.dt;
      y2[0].x = fmaf(rdlane(p0, 31), dtv, y2[0].x);
      y2[0].y = fmaf(rdlane(p1, 31), dtv, y2[0].y);
      y2[1].x = fmaf(rdlane(p2, 31), dtv, y2[1].x);
      y2[1].y = fmaf(rdlane(p3, 31), dtv, y2[1].y);
      y2[2].x = fmaf(rdlane(p0, 63), dtv, y2[2].x);
      y2[2].y = fmaf(rdlane(p1, 63), dtv, y2[2].y);
      y2[3].x = fmaf(rdlane(p2, 63), dtv, y2[3].x);
      y2[3].y = fmaf(rdlane(p3, 63), dtv, y2[3].y);

      // latch y_{inx} into lane (inx&63)'s ysave (pure VALU cndmask)
      const bool pr = (l == ((k + 1) & 63));
      ysv[0].x = pr ? y2[0].x : ysv[0].x;
      ysv[0].y = pr ? y2[0].y : ysv[0].y;
      ysv[1].x = pr ? y2[1].x : ysv[1].x;
      ysv[1].y = pr ? y2[1].y : ysv[1].y;
      ysv[2].x = pr ? y2[2].x : ysv[2].x;
      ysv[2].y = pr ? y2[2].y : ysv[2].y;
      ysv[3].x = pr ? y2[3].x : ysv[3].x;
      ysv[3].y = pr ? y2[3].y : ysv[3].y;
    };

    // first 4 pairs, then stage chunk c+1 (vmcnt has drained by then)
    #pragma unroll 1
    for (int kk = 0; kk < 8; kk += 2) { step(kk, P, Q); step(kk + 1, Q, P); }
    if (more) {
      *(float4*)&xbuf[((c + 1) & 1) * 512 + l * 8 + 0] = g0;
      *(float4*)&xbuf[((c + 1) & 1) * 512 + l * 8 + 4] = g1;
    }
    #pragma unroll 1
    for (int kk = 8; kk < 62; kk += 2) { step(kk, P, Q); step(kk + 1, Q, P); }
    step(62, P, Q);

    // ---- head burst: lane l handles tau = c*64 + l, y from register ysave ----
    {
      float ys[8] = {ysv[0].x, ysv[0].y, ysv[1].x, ysv[1].y,
                     ysv[2].x, ysv[2].y, ysv[3].x, ysv[3].y};
      float o0 = hw[110], o1 = hw[111];
      #pragma unroll
      for (int m = 0; m < 10; ++m) {
        float hh = hw[80 + m];
        #pragma unroll
        for (int s = 0; s < 8; ++s) hh = fmaf(ys[s], hw[s * 10 + m], hh);
        hh = fmaxf(hh, 0.0f);
        o0 = fmaf(hh, hw[90 + m * 2 + 0], o0);
        o1 = fmaf(hh, hw[90 + m * 2 + 1], o1);
      }
      out2[c * 64 + l] = make_float2(o0, o1);
    }

    if (more) step(63, Q, P);  // computes y_{(c+1)*64}, latches lane 0 for next window
  }
}

extern "C" void kernel_launch(void* const* d_in, const int* in_sizes, int n_in,
                              void* d_out, int out_size, void* d_ws, size_t ws_size,
                              hipStream_t stream) {
  const float* x   = (const float*)d_in[0];
  const float* t   = (const float*)d_in[1];
  const float* y0  = (const float*)d_in[2];
  const float* Wr1 = (const float*)d_in[3];
  const float* br1 = (const float*)d_in[4];
  const float* Wr2 = (const float*)d_in[5];
  const float* br2 = (const float*)d_in[6];
  const float* W1  = (const float*)d_in[7];
  const float* b1  = (const float*)d_in[8];
  const float* W2  = (const float*)d_in[9];
  const float* b2  = (const float*)d_in[10];
  (void)in_sizes; (void)n_in; (void)out_size; (void)d_ws; (void)ws_size;

  ode_scan_kernel<<<dim3(1024), dim3(64), 0, stream>>>(x, t, y0, Wr1, br1, Wr2,
                                                       br2, W1, b1, W2, b2,
                                                       (float*)d_out);
}